// Round 9
// baseline (151.289 us; speedup 1.0000x reference)
//
#include <hip/hip_runtime.h>
#include <hip/hip_bf16.h>

// MPNN fused pipeline, R20.  R19 post-mortem: d1's 1KB-stride fp32 gather
// (16x L1 traffic amplification) and d23's per-thread threadfences + 5%
// occupancy were the regressions; per-dispatch launch overhead is small.
// R20: 3 dispatches, all proven components:
//   prep_all  - R17b verbatim (minus Nacc zero; + ticket zero).
//   eg_gemm   - R17b job0 verbatim (e1,e2,G1,G2 via DMA from pre-swizzled Wt).
//   d23v2     - N/convert/final with 2x TLP: 256 blocks; N split S=32
//               (4 K-steps); convert sums 32 slabs; final re-tiled 64x128
//               (256 tiles exactly, dbuf, 48KB LDS); ticket barriers with
//               t==0-only release/acquire (no per-thread fences).

typedef short bf16x8  __attribute__((ext_vector_type(8)));
typedef short short4v __attribute__((ext_vector_type(4)));
typedef float f32x4   __attribute__((ext_vector_type(4)));

__device__ inline short f2bf(float x) {                // fp32 -> bf16 RNE
    unsigned u = __builtin_bit_cast(unsigned, x);
    return (short)((u + 0x7fffu + ((u >> 16) & 1u)) >> 16);
}
__device__ inline float bf2f(short b) {
    return __builtin_bit_cast(float, (unsigned)((unsigned short)b) << 16);
}
__device__ inline void cp16_async(const char* g, char* l) {
    __builtin_amdgcn_global_load_lds(
        (const __attribute__((address_space(1))) unsigned int*)g,
        (__attribute__((address_space(3))) unsigned int*)l, 16, 0, 0);
}

// --------------------------------------------------------------- core128
// 128x128-tile, BK=64, 4 waves 2x2, double-buffered cp16 DMA staging.
// Proven verbatim (R15b/R17b/R19, absmax 0.5).  Ends with __syncthreads().
__device__ __forceinline__ void core128(
    const short* __restrict__ Ap, int lda, const short* __restrict__ Bp, int ldb,
    int kbeg, int kend, int m0, int n0, short* Sf, f32x4 acc[4][4], int t)
{
    const int l = t & 63, lr = l & 15, q = l >> 4;
    const int w = t >> 6, wm = w >> 1, wn = w & 1;
    const int wub = t & ~63;

    auto stage = [&](int buf, int k0) {
        #pragma unroll
        for (int it = 0; it < 4; ++it) {
            int idx = it * 256 + t, r = idx >> 3, s = idx & 7;
            cp16_async((const char*)(Ap + (size_t)(m0 + r) * lda + k0) + s * 16,
                       (char*)(Sf + buf * 16384) + (size_t)(it * 256 + wub) * 16);
        }
        #pragma unroll
        for (int it = 0; it < 4; ++it) {
            int idx = it * 256 + t, r = idx >> 3, s = idx & 7;
            cp16_async((const char*)(Bp + (size_t)(n0 + r) * ldb + k0) + s * 16,
                       (char*)(Sf + buf * 16384 + 8192) + (size_t)(it * 256 + wub) * 16);
        }
    };

    stage(0, kbeg);
    __syncthreads();
    int cur = 0;
    for (int k0 = kbeg; k0 < kend; k0 += 64) {
        if (k0 + 64 < kend) stage(cur ^ 1, k0 + 64);
        const short* As = Sf + cur * 16384;
        const short* Bs = As + 8192;
        #pragma unroll
        for (int ks = 0; ks < 2; ++ks) {
            bf16x8 af[4], bfr[4];
            #pragma unroll
            for (int mt = 0; mt < 4; ++mt) {
                int ar = wm * 64 + mt * 16 + lr;
                af[mt] = *(const bf16x8*)&As[ar * 64 + (((ks*4 + q) ^ (ar & 7)) << 3)];
            }
            #pragma unroll
            for (int nt = 0; nt < 4; ++nt) {
                int br = wn * 64 + nt * 16 + lr;
                bfr[nt] = *(const bf16x8*)&Bs[br * 64 + (((ks*4 + q) ^ (br & 7)) << 3)];
            }
            #pragma unroll
            for (int mt = 0; mt < 4; ++mt)
                #pragma unroll
                for (int nt = 0; nt < 4; ++nt)
                    acc[mt][nt] = __builtin_amdgcn_mfma_f32_16x16x32_bf16(
                        af[mt], bfr[nt], acc[mt][nt], 0, 0, 0);
        }
        __syncthreads();
        cur ^= 1;
    }
}

// ------------------------------------------------------------------ prep_all
// R17b verbatim minus Nacc-zero; tw==320 block zeroes the tickets.
__global__ void prep_all(const float* __restrict__ X, short* __restrict__ h,
                         const float* __restrict__ W1, const float* __restrict__ W2,
                         const float* __restrict__ Wo,
                         short* __restrict__ Wt1, short* __restrict__ Wt2,
                         short* __restrict__ Wto1, short* __restrict__ Wto2,
                         short* __restrict__ Bt4, int* __restrict__ tick)
{
    __shared__ short tile[32][33];
    const int tx = threadIdx.x, ty = threadIdx.y;      // 32 x 8
    if (blockIdx.y < 8) {
        const int r0 = blockIdx.x * 32, c0 = blockIdx.y * 32;
        #pragma unroll
        for (int i = 0; i < 4; ++i) {
            int row = ty + i * 8;
            short b = f2bf(X[(size_t)(r0 + row) * 256 + c0 + tx]);
            int slot = ((((c0 & 32) + tx) >> 3) ^ ((r0 + row) & 7));
            h[(size_t)(r0 + row) * 768 + (c0 & ~63) + slot * 8 + (tx & 7)] = b;
        }
        return;
    }
    int tw = (blockIdx.y - 8) * 256 + blockIdx.x;
    if (tw >= 320) {
        if (tw == 320 && tx == 0 && ty == 0) { tick[0] = 0; tick[1] = 0; }
        return;
    }
    const float* src; short* dst; int ldwt, dk0, kx, ny;
    if (tw < 64)       { src = W1; dst = Wt1; ldwt = 256;
                         kx = tw >> 3; ny = tw & 7; dk0 = kx * 32; }
    else if (tw < 128) { int u = tw - 64; src = W2; dst = Wt2; ldwt = 256;
                         kx = u >> 3; ny = u & 7; dk0 = kx * 32; }
    else               { int u = tw - 128; int g = u >> 6; int rem = u & 63;
                         kx = rem >> 3; ny = rem & 7;
                         src = Wo + (size_t)g * 65536;
                         if (g == 0) { dst = Bt4; ldwt = 768; dk0 = kx * 32; }
                         else        { dst = (g == 1) ? Wto1 : Wto2;
                                       ldwt = 256; dk0 = kx * 32; } }
    const int k0l = kx * 32, n0 = ny * 32;
    #pragma unroll
    for (int i = 0; i < 4; ++i) {
        int row = ty + i * 8;
        tile[row][tx] = f2bf(src[(size_t)(k0l + row) * 256 + n0 + tx]);
    }
    __syncthreads();
    #pragma unroll
    for (int i = 0; i < 4; ++i) {
        int row = ty + i * 8;
        int n = n0 + row;
        int slot = ((((dk0 & 32) + tx) >> 3) ^ (n & 7));
        dst[(size_t)n * ldwt + (dk0 & ~63) + slot * 8 + (tx & 7)] = tile[tx][row];
    }
}

// ------------------------------------------------------------------ eg_gemm
// R17b job0 verbatim: grid (64,2,4).  z: 0=e1, 1=e2, 2=G1, 3=G2.
__global__ __launch_bounds__(256, 1)
void eg_gemm(short* __restrict__ h,
             const short* __restrict__ Wt1, const short* __restrict__ Wt2,
             const short* __restrict__ Wto1, const short* __restrict__ Wto2,
             const float* __restrict__ b1, const float* __restrict__ b2,
             short* __restrict__ e1t, short* __restrict__ e2t,
             short* __restrict__ G1t, short* __restrict__ G2t)
{
    const int z = blockIdx.z;
    const int mode = (z < 2) ? 1 : 3;
    const int sim  = z & 1;
    const short* Bp   = (z == 0) ? Wt1 : (z == 1) ? Wt2 : (z == 2) ? Wto1 : Wto2;
    const float* bias = (z == 0) ? b1  : (z == 1) ? b2  : nullptr;
    short* et         = (z == 0) ? e1t : (z == 1) ? e2t : (z == 2) ? G1t : G2t;

    const int m0 = blockIdx.x * 128, n0 = blockIdx.y * 128;
    const int t = threadIdx.x;
    const int l = t & 63, lr = l & 15, q = l >> 4;
    const int w = t >> 6, wm = w >> 1, wn = w & 1;

    __shared__ __attribute__((aligned(16))) short S[32768];

    f32x4 acc[4][4];
    #pragma unroll
    for (int i = 0; i < 4; ++i)
        #pragma unroll
        for (int j = 0; j < 4; ++j) acc[i][j] = f32x4{0.f, 0.f, 0.f, 0.f};

    core128(h, 768, Bp, 256, 0, 256, m0, n0, S, acc, t);

    // epilogue: R17b mode 1/3 verbatim
    short* Hs = S;
    short* Ts = S + 16384;
    #pragma unroll
    for (int mt = 0; mt < 4; ++mt)
        #pragma unroll
        for (int nt = 0; nt < 4; ++nt) {
            int n_loc = wn * 64 + nt * 16 + lr;
            float bb = (mode == 1) ? bias[n0 + n_loc] : 0.f;
            short vb[4];
            #pragma unroll
            for (int r = 0; r < 4; ++r) {
                float v = acc[mt][nt][r] + bb;
                if (mode == 1) v = v > 0.f ? v : 0.f;
                vb[r] = f2bf(v);
                if (mode == 1) {
                    int m_loc = wm * 64 + mt * 16 + q * 4 + r;
                    Hs[m_loc * 128 + n_loc] = vb[r];
                }
            }
            int gm = wm * 8 + mt * 2 + (q >> 1);
            short4v pk = { vb[0], vb[1], vb[2], vb[3] };
            *(short4v*)&Ts[n_loc * 128 + ((gm >> 3) << 6)
                           + (((gm & 7) ^ (n_loc & 7)) << 3) + ((q & 1) << 2)] = pk;
        }
    __syncthreads();
    if (mode == 1) {
        const int cb = 256 + sim * 256 + n0;
        for (int i = t; i < 2048; i += 256) {
            int ml = i >> 4, g = i & 15;
            bf16x8 hv = *(const bf16x8*)&Hs[ml * 128 + g * 8];
            *(bf16x8*)(h + (size_t)(m0 + ml) * 768 + cb + ((g >> 3) << 6)
                       + (((g & 7) ^ (ml & 7)) << 3)) = hv;
        }
    }
    for (int i = t; i < 2048; i += 256) {
        int nl = i >> 4, s = i & 15;
        bf16x8 tv = *(const bf16x8*)&Ts[nl * 128 + s * 8];
        *(bf16x8*)(et + (size_t)(n0 + nl) * 8192 + m0 + s * 8) = tv;
    }
}

// ------------------------------------------------------------------ d23v2
// grid (256), 256 thr, 64KB LDS -> 2 blocks/CU, capacity 512 >> 256 (safe
// co-residency for ticket barriers).
// Phase N: 256 jobs = 2bx x 2by x (2sim x 32split); K window 256 (4 steps);
//          slab stores (each slab quadrant written by exactly one block).
// Ticket0 -> convert: 16384 granules over 256 blocks x 64 thr, sum 32 slabs,
//          -> Bt4 cols 256:768 (swizzled, verbatim math).
// Ticket1 -> final: 256 tiles of 64m x 128n, K=768, dbuf 48KB.
__global__ __launch_bounds__(256, 1)
void d23v2(const short* __restrict__ e1t, const short* __restrict__ e2t,
           const short* __restrict__ G1t, const short* __restrict__ G2t,
           const short* __restrict__ h, short* __restrict__ Bt4,
           float* __restrict__ Nslab, int* __restrict__ ticket,
           const float* __restrict__ bov, float* __restrict__ outf)
{
    const int fb = blockIdx.x, t = threadIdx.x;
    const int l = t & 63, lr = l & 15, q = l >> 4;
    const int w = t >> 6, wm = w >> 1, wn = w & 1, wub = t & ~63;

    __shared__ __attribute__((aligned(16))) short S[32768];   // 64 KB

    // ---- phase N ----
    {
        const int bx = fb & 1, by = (fb >> 1) & 1, bz = fb >> 2;  // bz 0..63
        const int sim = bz & 1, split = bz >> 1;                  // split 0..31
        const int kbeg = split * 256, m0 = bx * 128, n0 = by * 128;
        const short* Ap = sim ? G2t : G1t;
        const short* Bp = sim ? e2t : e1t;

        f32x4 acc[4][4];
        #pragma unroll
        for (int i = 0; i < 4; ++i)
            #pragma unroll
            for (int j = 0; j < 4; ++j) acc[i][j] = f32x4{0.f, 0.f, 0.f, 0.f};
        core128(Ap, 8192, Bp, 8192, kbeg, kbeg + 256, m0, n0, S, acc, t);

        float* Mo = Nslab + (size_t)(split * 2 + sim) * 65536;
        #pragma unroll
        for (int mt = 0; mt < 4; ++mt)
            #pragma unroll
            for (int nt = 0; nt < 4; ++nt)
                #pragma unroll
                for (int r = 0; r < 4; ++r) {
                    int m = m0 + wm * 64 + mt * 16 + q * 4 + r;
                    int n = n0 + wn * 64 + nt * 16 + lr;
                    Mo[(size_t)m * 256 + n] = acc[mt][nt][r] * (1.0f / 256.0f);
                }
    }

    // ---- ticket 0 (release/acquire on t==0 only) ----
    __syncthreads();
    if (t == 0) {
        __hip_atomic_fetch_add(&ticket[0], 1, __ATOMIC_RELEASE, __HIP_MEMORY_SCOPE_AGENT);
        while (__hip_atomic_load(&ticket[0], __ATOMIC_ACQUIRE, __HIP_MEMORY_SCOPE_AGENT) < 256)
            __builtin_amdgcn_s_sleep(8);
    }
    __syncthreads();

    // ---- convert: 64 granules per block ----
    if (t < 64) {
        int gid = fb * 64 + t;                 // 0..16383
        int simg = gid >> 13, rem = gid & 8191;
        int n = rem >> 5, g = rem & 31;
        f32x4 sa = f32x4{0.f, 0.f, 0.f, 0.f}, sb = f32x4{0.f, 0.f, 0.f, 0.f};
        #pragma unroll 4
        for (int s = 0; s < 32; ++s) {
            const float* np = Nslab + (size_t)(s * 2 + simg) * 65536
                              + (size_t)n * 256 + g * 8;
            sa += *(const f32x4*)np;
            sb += *(const f32x4*)(np + 4);
        }
        bf16x8 pk;
        pk[0] = f2bf(sa[0]); pk[1] = f2bf(sa[1]);
        pk[2] = f2bf(sa[2]); pk[3] = f2bf(sa[3]);
        pk[4] = f2bf(sb[0]); pk[5] = f2bf(sb[1]);
        pk[6] = f2bf(sb[2]); pk[7] = f2bf(sb[3]);
        int k = 256 + simg * 256 + g * 8;
        int slot = (g & 7) ^ (n & 7);
        *(bf16x8*)(Bt4 + (size_t)n * 768 + (k & ~63) + slot * 8) = pk;
    }

    // ---- ticket 1 ----
    __syncthreads();
    if (t == 0) {
        __hip_atomic_fetch_add(&ticket[1], 1, __ATOMIC_RELEASE, __HIP_MEMORY_SCOPE_AGENT);
        while (__hip_atomic_load(&ticket[1], __ATOMIC_ACQUIRE, __HIP_MEMORY_SCOPE_AGENT) < 256)
            __builtin_amdgcn_s_sleep(8);
    }
    __syncthreads();

    // ---- final: 64x128 tile, K=768, dbuf (A 8KB + B 16KB per buf = 48KB) ----
    {
        const int m0 = (fb >> 1) * 64, n0 = (fb & 1) * 128;
        f32x4 acc[2][4];
        #pragma unroll
        for (int i = 0; i < 2; ++i)
            #pragma unroll
            for (int j = 0; j < 4; ++j) acc[i][j] = f32x4{0.f, 0.f, 0.f, 0.f};

        auto stage = [&](int buf, int k0) {
            #pragma unroll
            for (int it = 0; it < 2; ++it) {   // A: 64 rows x 8 granules
                int idx = it * 256 + t, r = idx >> 3, s = idx & 7;
                cp16_async((const char*)(h + (size_t)(m0 + r) * 768 + k0) + s * 16,
                           (char*)(S + buf * 12288) + (size_t)(it * 256 + wub) * 16);
            }
            #pragma unroll
            for (int it = 0; it < 4; ++it) {   // B: 128 rows x 8 granules
                int idx = it * 256 + t, r = idx >> 3, s = idx & 7;
                cp16_async((const char*)(Bt4 + (size_t)(n0 + r) * 768 + k0) + s * 16,
                           (char*)(S + buf * 12288 + 4096) + (size_t)(it * 256 + wub) * 16);
            }
        };

        stage(0, 0);
        __syncthreads();
        int cur = 0;
        for (int k0 = 0; k0 < 768; k0 += 64) {
            if (k0 + 64 < 768) stage(cur ^ 1, k0 + 64);
            const short* As = S + cur * 12288;
            const short* Bs = As + 4096;
            #pragma unroll
            for (int ks = 0; ks < 2; ++ks) {
                bf16x8 af[2], bfr[4];
                #pragma unroll
                for (int mt = 0; mt < 2; ++mt) {
                    int ar = wm * 32 + mt * 16 + lr;
                    af[mt] = *(const bf16x8*)&As[ar * 64 + (((ks*4 + q) ^ (ar & 7)) << 3)];
                }
                #pragma unroll
                for (int nt = 0; nt < 4; ++nt) {
                    int br = wn * 64 + nt * 16 + lr;
                    bfr[nt] = *(const bf16x8*)&Bs[br * 64 + (((ks*4 + q) ^ (br & 7)) << 3)];
                }
                #pragma unroll
                for (int mt = 0; mt < 2; ++mt)
                    #pragma unroll
                    for (int nt = 0; nt < 4; ++nt)
                        acc[mt][nt] = __builtin_amdgcn_mfma_f32_16x16x32_bf16(
                            af[mt], bfr[nt], acc[mt][nt], 0, 0, 0);
            }
            __syncthreads();
            cur ^= 1;
        }

        #pragma unroll
        for (int mt = 0; mt < 2; ++mt)
            #pragma unroll
            for (int nt = 0; nt < 4; ++nt)
                #pragma unroll
                for (int r = 0; r < 4; ++r) {
                    int m = m0 + wm * 32 + mt * 16 + q * 4 + r;
                    int n = n0 + wn * 64 + nt * 16 + lr;
                    float v = acc[mt][nt][r] + bov[n];
                    outf[(size_t)m * 256 + n] = v > 0.f ? v : 0.f;
                }
    }
}

// ---------------------------------------------------------------- launch
extern "C" void kernel_launch(void* const* d_in, const int* in_sizes, int n_in,
                              void* d_out, int out_size, void* d_ws, size_t ws_size,
                              hipStream_t stream)
{
    const float* edge_x = (const float*)d_in[0];
    const float* W1 = (const float*)d_in[1];
    const float* b1 = (const float*)d_in[2];
    const float* W2 = (const float*)d_in[3];
    const float* b2 = (const float*)d_in[4];
    const float* Wo = (const float*)d_in[5];
    const float* bo = (const float*)d_in[6];

    // workspace (~47.1 MB; poison fill shows ws >= 256 MB)
    char* ws = (char*)d_ws;
    short* h     = (short*)ws;                   // [8192][768] bf16 swz 12,582,912
    short* e1t   = (short*)(ws + 12582912);      // [256][8192] bf16 swz  4,194,304
    short* e2t   = (short*)(ws + 16777216);      // [256][8192] bf16 swz  4,194,304
    short* G1t   = (short*)(ws + 20971520);      // [256][8192] bf16 swz  4,194,304
    short* G2t   = (short*)(ws + 25165824);      // [256][8192] bf16 swz  4,194,304
    short* Wt1   = (short*)(ws + 29360128);      // [256][256]  bf16 swz    131,072
    short* Wt2   = (short*)(ws + 29491200);      // [256][256]  bf16 swz    131,072
    short* Wto1  = (short*)(ws + 29622272);      // [256][256]  bf16 swz    131,072
    short* Wto2  = (short*)(ws + 29753344);      // [256][256]  bf16 swz    131,072
    short* Bt4   = (short*)(ws + 29884416);      // [256][768]  bf16 swz    393,216
    float* Nslab = (float*)(ws + 30277632);      // [64][256][256] fp32  16,777,216
    int*   tick  = (int*)(ws + 47054848);        // 2 ints

    float* out = (float*)d_out;

    prep_all<<<dim3(256, 10), dim3(32, 8), 0, stream>>>(
        edge_x, h, W1, W2, Wo, Wt1, Wt2, Wto1, Wto2, Bt4, tick);

    eg_gemm<<<dim3(64, 2, 4), 256, 0, stream>>>(
        h, Wt1, Wt2, Wto1, Wto2, b1, b2, e1t, e2t, G1t, G2t);

    d23v2<<<dim3(256), 256, 0, stream>>>(
        e1t, e2t, G1t, G2t, h, Bt4, Nslab, tick, bo, out);
}

// Round 10
// 121.275 us; speedup vs baseline: 1.2475x; 1.2475x over previous
//
#include <hip/hip_runtime.h>
#include <hip/hip_bf16.h>

// MPNN fused pipeline, R21.  Budget (consistent across R0-R20): gaps ~5us,
// eg_gemm ~40-45us, prep ~20-30us, job1 ~20us, final ~15us.  R20's in-kernel
// barriers were worse than dispatch boundaries -> back to the R17b 5-dispatch
// skeleton.  New mechanism (eg + final only): B panel fits LDS entirely
// (128x256 bf16 = 64KB), so stage B ONCE (one barrier) and stream A-fragments
// DIRECTLY global->VGPR (granule swizzle makes each fragment a contiguous
// aligned 16B load).  Zero barriers in the MFMA K-loop; compiler counts vmcnt
// and pipelines ~32 in-flight loads (pattern that gave R0's simagg 37% MFMA
// util).  Fragment bytes + k-order + epilogues identical to R17b ->
// bit-identical outputs (absmax must stay exactly 0.5).
// prep_all / job1 (core128 split-K atomics) / convert_n: R17b verbatim.

typedef short bf16x8  __attribute__((ext_vector_type(8)));
typedef short short4v __attribute__((ext_vector_type(4)));
typedef float f32x4   __attribute__((ext_vector_type(4)));

__device__ inline short f2bf(float x) {                // fp32 -> bf16 RNE
    unsigned u = __builtin_bit_cast(unsigned, x);
    return (short)((u + 0x7fffu + ((u >> 16) & 1u)) >> 16);
}
__device__ inline float bf2f(short b) {
    return __builtin_bit_cast(float, (unsigned)((unsigned short)b) << 16);
}
__device__ inline void cp16_async(const char* g, char* l) {
    __builtin_amdgcn_global_load_lds(
        (const __attribute__((address_space(1))) unsigned int*)g,
        (__attribute__((address_space(3))) unsigned int*)l, 16, 0, 0);
}

// ------------------------------------------------------------------ prep_all
// R17b verbatim.  grid (256,10), block (32,8).
__global__ void prep_all(const float* __restrict__ X, short* __restrict__ h,
                         const float* __restrict__ W1, const float* __restrict__ W2,
                         const float* __restrict__ Wo,
                         short* __restrict__ Wt1, short* __restrict__ Wt2,
                         short* __restrict__ Wto1, short* __restrict__ Wto2,
                         short* __restrict__ Bt4, float* __restrict__ Nacc)
{
    __shared__ short tile[32][33];
    const int tx = threadIdx.x, ty = threadIdx.y;      // 32 x 8
    if (blockIdx.y < 8) {
        const int r0 = blockIdx.x * 32, c0 = blockIdx.y * 32;
        #pragma unroll
        for (int i = 0; i < 4; ++i) {
            int row = ty + i * 8;
            short b = f2bf(X[(size_t)(r0 + row) * 256 + c0 + tx]);
            int slot = ((((c0 & 32) + tx) >> 3) ^ ((r0 + row) & 7));
            h[(size_t)(r0 + row) * 768 + (c0 & ~63) + slot * 8 + (tx & 7)] = b;
        }
        return;
    }
    int tw = (blockIdx.y - 8) * 256 + blockIdx.x;
    if (tw >= 320) {                               // zero Nacc with idle blocks
        int i0 = (tw - 320) * 256 + ty * 32 + tx;
        for (int i = i0; i < 131072; i += 49152) Nacc[i] = 0.f;
        return;
    }
    const float* src; short* dst; int ldwt, dk0, kx, ny;
    if (tw < 64)       { src = W1; dst = Wt1; ldwt = 256;
                         kx = tw >> 3; ny = tw & 7; dk0 = kx * 32; }
    else if (tw < 128) { int u = tw - 64; src = W2; dst = Wt2; ldwt = 256;
                         kx = u >> 3; ny = u & 7; dk0 = kx * 32; }
    else               { int u = tw - 128; int g = u >> 6; int rem = u & 63;
                         kx = rem >> 3; ny = rem & 7;
                         src = Wo + (size_t)g * 65536;
                         if (g == 0) { dst = Bt4; ldwt = 768; dk0 = kx * 32; }
                         else        { dst = (g == 1) ? Wto1 : Wto2;
                                       ldwt = 256; dk0 = kx * 32; } }
    const int k0l = kx * 32, n0 = ny * 32;
    #pragma unroll
    for (int i = 0; i < 4; ++i) {
        int row = ty + i * 8;
        tile[row][tx] = f2bf(src[(size_t)(k0l + row) * 256 + n0 + tx]);
    }
    __syncthreads();
    #pragma unroll
    for (int i = 0; i < 4; ++i) {
        int row = ty + i * 8;
        int n = n0 + row;
        int slot = ((((dk0 & 32) + tx) >> 3) ^ (n & 7));
        dst[(size_t)n * ldwt + (dk0 & ~63) + slot * 8 + (tx & 7)] = tile[tx][row];
    }
}

// ------------------------------------------------------------------ eg_v2
// grid (64,2,4).  z: 0=e1, 1=e2, 2=G1, 3=G2.  B panel (128x256 bf16, 64KB)
// staged to LDS once; A fragments streamed global->VGPR; no K-loop barriers.
// Epilogue: R17b mode 1/3 verbatim (Hs/Ts reuse the B LDS after a barrier).
__global__ __launch_bounds__(256, 1)
void eg_v2(const short* __restrict__ h,
           const short* __restrict__ Wt1, const short* __restrict__ Wt2,
           const short* __restrict__ Wto1, const short* __restrict__ Wto2,
           const float* __restrict__ b1, const float* __restrict__ b2,
           short* __restrict__ hw, short* __restrict__ e1t, short* __restrict__ e2t,
           short* __restrict__ G1t, short* __restrict__ G2t)
{
    const int z = blockIdx.z;
    const int mode = (z < 2) ? 1 : 3;
    const int sim  = z & 1;
    const short* Bp   = (z == 0) ? Wt1 : (z == 1) ? Wt2 : (z == 2) ? Wto1 : Wto2;
    const float* bias = (z == 0) ? b1  : (z == 1) ? b2  : nullptr;
    short* et         = (z == 0) ? e1t : (z == 1) ? e2t : (z == 2) ? G1t : G2t;

    const int m0 = blockIdx.x * 128, n0 = blockIdx.y * 128;
    const int t = threadIdx.x;
    const int l = t & 63, lr = l & 15, q = l >> 4;
    const int w = t >> 6, wm = w >> 1, wn = w & 1, wub = t & ~63;

    __shared__ __attribute__((aligned(16))) short Bs[32768];   // 64 KB

    // stage whole B panel: 4096 granules = 16 per thread
    #pragma unroll
    for (int it = 0; it < 16; ++it) {
        int idx = it * 256 + t, r = idx >> 5, s = idx & 31;
        cp16_async((const char*)(Bp + (size_t)(n0 + r) * 256) + s * 16,
                   (char*)Bs + (size_t)(it * 256 + wub) * 16);
    }
    __syncthreads();                           // single drain; Bs read-only

    f32x4 acc[4][4];
    #pragma unroll
    for (int i = 0; i < 4; ++i)
        #pragma unroll
        for (int j = 0; j < 4; ++j) acc[i][j] = f32x4{0.f, 0.f, 0.f, 0.f};

    #pragma unroll
    for (int kb = 0; kb < 4; ++kb)             // 64-col K-blocks (ascending k)
        #pragma unroll
        for (int ks = 0; ks < 2; ++ks) {
            const int g = ks * 4 + q;
            bf16x8 af[4], bfr[4];
            #pragma unroll
            for (int mt = 0; mt < 4; ++mt) {   // A: global -> VGPR (16B each)
                int ar = wm * 64 + mt * 16 + lr;
                af[mt] = *(const bf16x8*)(h + (size_t)(m0 + ar) * 768
                                          + kb * 64 + ((g ^ (ar & 7)) << 3));
            }
            #pragma unroll
            for (int nt = 0; nt < 4; ++nt) {
                int br = wn * 64 + nt * 16 + lr;
                bfr[nt] = *(const bf16x8*)&Bs[br * 256 + kb * 64
                                              + ((g ^ (br & 7)) << 3)];
            }
            #pragma unroll
            for (int mt = 0; mt < 4; ++mt)
                #pragma unroll
                for (int nt = 0; nt < 4; ++nt)
                    acc[mt][nt] = __builtin_amdgcn_mfma_f32_16x16x32_bf16(
                        af[mt], bfr[nt], acc[mt][nt], 0, 0, 0);
        }

    // epilogue (R17b verbatim): Hs row-major (mode 1), Ts transposed+swizzled
    __syncthreads();                           // all Bs readers done
    short* Hs = Bs;                            // [128][128]
    short* Ts = Bs + 16384;                    // [128][128]
    #pragma unroll
    for (int mt = 0; mt < 4; ++mt)
        #pragma unroll
        for (int nt = 0; nt < 4; ++nt) {
            int n_loc = wn * 64 + nt * 16 + lr;
            float bb = (mode == 1) ? bias[n0 + n_loc] : 0.f;
            short vb[4];
            #pragma unroll
            for (int r = 0; r < 4; ++r) {
                float v = acc[mt][nt][r] + bb;
                if (mode == 1) v = v > 0.f ? v : 0.f;
                vb[r] = f2bf(v);
                if (mode == 1) {
                    int m_loc = wm * 64 + mt * 16 + q * 4 + r;
                    Hs[m_loc * 128 + n_loc] = vb[r];
                }
            }
            int gm = wm * 8 + mt * 2 + (q >> 1);
            short4v pk = { vb[0], vb[1], vb[2], vb[3] };
            *(short4v*)&Ts[n_loc * 128 + ((gm >> 3) << 6)
                           + (((gm & 7) ^ (n_loc & 7)) << 3) + ((q & 1) << 2)] = pk;
        }
    __syncthreads();
    if (mode == 1) {
        const int cb = 256 + sim * 256 + n0;
        for (int i = t; i < 2048; i += 256) {
            int ml = i >> 4, g = i & 15;
            bf16x8 hv = *(const bf16x8*)&Hs[ml * 128 + g * 8];
            *(bf16x8*)(hw + (size_t)(m0 + ml) * 768 + cb + ((g >> 3) << 6)
                       + (((g & 7) ^ (ml & 7)) << 3)) = hv;
        }
    }
    for (int i = t; i < 2048; i += 256) {
        int nl = i >> 4, s = i & 15;
        bf16x8 tv = *(const bf16x8*)&Ts[nl * 128 + s * 8];
        *(bf16x8*)(et + (size_t)(n0 + nl) * 8192 + m0 + s * 8) = tv;
    }
}

// --------------------------------------------------------------- core128
// R17b verbatim (used by nacc_gemm only).
__device__ __forceinline__ void core128(
    const short* __restrict__ Ap, int lda, const short* __restrict__ Bp, int ldb,
    int kbeg, int kend, int m0, int n0, short* Sf, f32x4 acc[4][4], int t)
{
    const int l = t & 63, lr = l & 15, q = l >> 4;
    const int w = t >> 6, wm = w >> 1, wn = w & 1;
    const int wub = t & ~63;

    auto stage = [&](int buf, int k0) {
        #pragma unroll
        for (int it = 0; it < 4; ++it) {
            int idx = it * 256 + t, r = idx >> 3, s = idx & 7;
            cp16_async((const char*)(Ap + (size_t)(m0 + r) * lda + k0) + s * 16,
                       (char*)(Sf + buf * 16384) + (size_t)(it * 256 + wub) * 16);
        }
        #pragma unroll
        for (int it = 0; it < 4; ++it) {
            int idx = it * 256 + t, r = idx >> 3, s = idx & 7;
            cp16_async((const char*)(Bp + (size_t)(n0 + r) * ldb + k0) + s * 16,
                       (char*)(Sf + buf * 16384 + 8192) + (size_t)(it * 256 + wub) * 16);
        }
    };

    stage(0, kbeg);
    __syncthreads();
    int cur = 0;
    for (int k0 = kbeg; k0 < kend; k0 += 64) {
        if (k0 + 64 < kend) stage(cur ^ 1, k0 + 64);
        const short* As = Sf + cur * 16384;
        const short* Bs2 = As + 8192;
        #pragma unroll
        for (int ks = 0; ks < 2; ++ks) {
            bf16x8 af[4], bfr[4];
            #pragma unroll
            for (int mt = 0; mt < 4; ++mt) {
                int ar = wm * 64 + mt * 16 + lr;
                af[mt] = *(const bf16x8*)&As[ar * 64 + (((ks*4 + q) ^ (ar & 7)) << 3)];
            }
            #pragma unroll
            for (int nt = 0; nt < 4; ++nt) {
                int br = wn * 64 + nt * 16 + lr;
                bfr[nt] = *(const bf16x8*)&Bs2[br * 64 + (((ks*4 + q) ^ (br & 7)) << 3)];
            }
            #pragma unroll
            for (int mt = 0; mt < 4; ++mt)
                #pragma unroll
                for (int nt = 0; nt < 4; ++nt)
                    acc[mt][nt] = __builtin_amdgcn_mfma_f32_16x16x32_bf16(
                        af[mt], bfr[nt], acc[mt][nt], 0, 0, 0);
        }
        __syncthreads();
        cur ^= 1;
    }
}

// ---------------------------------------------------------- nacc_gemm
// R17b job1 verbatim: grid (2,2,32); Nacc[sim] += (G^T e)/256, split-K 16.
__global__ __launch_bounds__(256, 1)
void nacc_gemm(const short* __restrict__ e1t, const short* __restrict__ e2t,
               const short* __restrict__ G1t, const short* __restrict__ G2t,
               float* __restrict__ Nacc)
{
    const int z = blockIdx.z;
    const int sim = z & 1;
    const int kbeg = (z >> 1) * 512;
    const short* Ap = sim ? G2t : G1t;
    const short* Bp = sim ? e2t : e1t;
    const int m0 = blockIdx.x * 128, n0 = blockIdx.y * 128;
    const int t = threadIdx.x;
    const int l = t & 63, lr = l & 15, q = l >> 4;
    const int w = t >> 6, wm = w >> 1, wn = w & 1;

    __shared__ __attribute__((aligned(16))) short S[32768];

    f32x4 acc[4][4];
    #pragma unroll
    for (int i = 0; i < 4; ++i)
        #pragma unroll
        for (int j = 0; j < 4; ++j) acc[i][j] = f32x4{0.f, 0.f, 0.f, 0.f};

    core128(Ap, 8192, Bp, 8192, kbeg, kbeg + 512, m0, n0, S, acc, t);

    float* Mo = Nacc + (size_t)sim * 65536;
    #pragma unroll
    for (int mt = 0; mt < 4; ++mt)
        #pragma unroll
        for (int nt = 0; nt < 4; ++nt)
            #pragma unroll
            for (int r = 0; r < 4; ++r) {
                int m = m0 + wm * 64 + mt * 16 + q * 4 + r;
                int n = n0 + wn * 64 + nt * 16 + lr;
                atomicAdd(&Mo[(size_t)m * 256 + n],
                          acc[mt][nt][r] * (1.0f / 256.0f));
            }
}

// ---------------------------------------------------------- convert_n
// R17b verbatim.  grid (64), block (256).
__global__ void convert_n(const float* __restrict__ Nacc, short* __restrict__ Bt4)
{
    int gid = blockIdx.x * 256 + threadIdx.x;      // 0..16383
    int sim = gid >> 13, rem = gid & 8191;
    int n = rem >> 5, g = rem & 31;
    const float* np = Nacc + (size_t)sim * 65536 + (size_t)n * 256 + g * 8;
    f32x4 va = *(const f32x4*)np;
    f32x4 vb = *(const f32x4*)(np + 4);
    bf16x8 pk;
    pk[0] = f2bf(va[0]); pk[1] = f2bf(va[1]);
    pk[2] = f2bf(va[2]); pk[3] = f2bf(va[3]);
    pk[4] = f2bf(vb[0]); pk[5] = f2bf(vb[1]);
    pk[6] = f2bf(vb[2]); pk[7] = f2bf(vb[3]);
    int k = 256 + sim * 256 + g * 8;               // global column
    int slot = (g & 7) ^ (n & 7);
    *(bf16x8*)(Bt4 + (size_t)n * 768 + (k & ~63) + slot * 8) = pk;
}

// ------------------------------------------------------------------ final_v2
// grid (64,2).  out = relu(h @ Bt4^T + bo), K=768 in 3 chunks of 256:
// per chunk, stage B (128x256, 64KB) -> one barrier -> A-streamed MFMA
// (no inner barriers).  k-order identical to R17b -> bit-identical rounding.
__global__ __launch_bounds__(256, 1)
void final_v2(const short* __restrict__ h, const short* __restrict__ Bt4,
              const float* __restrict__ bov, float* __restrict__ outf)
{
    const int m0 = blockIdx.x * 128, n0 = blockIdx.y * 128;
    const int t = threadIdx.x;
    const int l = t & 63, lr = l & 15, q = l >> 4;
    const int w = t >> 6, wm = w >> 1, wn = w & 1, wub = t & ~63;

    __shared__ __attribute__((aligned(16))) short Bs[32768];   // 64 KB

    f32x4 acc[4][4];
    #pragma unroll
    for (int i = 0; i < 4; ++i)
        #pragma unroll
        for (int j = 0; j < 4; ++j) acc[i][j] = f32x4{0.f, 0.f, 0.f, 0.f};

    for (int kc = 0; kc < 3; ++kc) {
        if (kc) __syncthreads();               // prev-chunk readers done
        #pragma unroll
        for (int it = 0; it < 16; ++it) {      // stage B chunk: 4096 granules
            int idx = it * 256 + t, r = idx >> 5, s = idx & 31;
            cp16_async((const char*)(Bt4 + (size_t)(n0 + r) * 768 + kc * 256) + s * 16,
                       (char*)Bs + (size_t)(it * 256 + wub) * 16);
        }
        __syncthreads();                       // drain; Bs read-only for chunk

        #pragma unroll
        for (int kb = 0; kb < 4; ++kb)
            #pragma unroll
            for (int ks = 0; ks < 2; ++ks) {
                const int g = ks * 4 + q;
                bf16x8 af[4], bfr[4];
                #pragma unroll
                for (int mt = 0; mt < 4; ++mt) {
                    int ar = wm * 64 + mt * 16 + lr;
                    af[mt] = *(const bf16x8*)(h + (size_t)(m0 + ar) * 768
                                              + kc * 256 + kb * 64
                                              + ((g ^ (ar & 7)) << 3));
                }
                #pragma unroll
                for (int nt = 0; nt < 4; ++nt) {
                    int br = wn * 64 + nt * 16 + lr;
                    bfr[nt] = *(const bf16x8*)&Bs[br * 256 + kb * 64
                                                  + ((g ^ (br & 7)) << 3)];
                }
                #pragma unroll
                for (int mt = 0; mt < 4; ++mt)
                    #pragma unroll
                    for (int nt = 0; nt < 4; ++nt)
                        acc[mt][nt] = __builtin_amdgcn_mfma_f32_16x16x32_bf16(
                            af[mt], bfr[nt], acc[mt][nt], 0, 0, 0);
            }
    }

    #pragma unroll
    for (int mt = 0; mt < 4; ++mt)
        #pragma unroll
        for (int nt = 0; nt < 4; ++nt)
            #pragma unroll
            for (int r = 0; r < 4; ++r) {
                int m = m0 + wm * 64 + mt * 16 + q * 4 + r;
                int n = n0 + wn * 64 + nt * 16 + lr;
                float v = acc[mt][nt][r] + bov[n];
                outf[(size_t)m * 256 + n] = v > 0.f ? v : 0.f;
            }
}

// ---------------------------------------------------------------- launch
extern "C" void kernel_launch(void* const* d_in, const int* in_sizes, int n_in,
                              void* d_out, int out_size, void* d_ws, size_t ws_size,
                              hipStream_t stream)
{
    const float* edge_x = (const float*)d_in[0];
    const float* W1 = (const float*)d_in[1];
    const float* b1 = (const float*)d_in[2];
    const float* W2 = (const float*)d_in[3];
    const float* b2 = (const float*)d_in[4];
    const float* Wo = (const float*)d_in[5];
    const float* bo = (const float*)d_in[6];

    // workspace (~31 MB; poison fill shows ws >= 256 MB)
    char* ws = (char*)d_ws;
    short* h    = (short*)ws;                    // [8192][768] bf16 swz  12,582,912
    short* e1t  = (short*)(ws + 12582912);       // [256][8192] bf16 swz   4,194,304
    short* e2t  = (short*)(ws + 16777216);       // [256][8192] bf16 swz   4,194,304
    short* G1t  = (short*)(ws + 20971520);       // [256][8192] bf16 swz   4,194,304
    short* G2t  = (short*)(ws + 25165824);       // [256][8192] bf16 swz   4,194,304
    short* Wt1  = (short*)(ws + 29360128);       // [256][256]  bf16 swz     131,072
    short* Wt2  = (short*)(ws + 29491200);       // [256][256]  bf16 swz     131,072
    short* Wto1 = (short*)(ws + 29622272);       // [256][256]  bf16 swz     131,072
    short* Wto2 = (short*)(ws + 29753344);       // [256][256]  bf16 swz     131,072
    short* Bt4  = (short*)(ws + 29884416);       // [256][768]  bf16 swz     393,216
    float* Nacc = (float*)(ws + 30277632);       // [2][256][256] fp32       524,288

    float* out = (float*)d_out;

    prep_all<<<dim3(256, 10), dim3(32, 8), 0, stream>>>(
        edge_x, h, W1, W2, Wo, Wt1, Wt2, Wto1, Wto2, Bt4, Nacc);

    // e1/e2 -> h cols + e_it ; G1/G2 -> G_it  (B-resident, A-streamed)
    eg_v2<<<dim3(64, 2, 4), 256, 0, stream>>>(
        h, Wt1, Wt2, Wto1, Wto2, b1, b2, h, e1t, e2t, G1t, G2t);

    // Nacc[sim] = (G_sim^T e_sim)/256  (split-K 16, atomics)
    nacc_gemm<<<dim3(2, 2, 32), 256, 0, stream>>>(e1t, e2t, G1t, G2t, Nacc);

    // N^T -> Bt4 cols 256:768 (bf16, swizzled)
    convert_n<<<dim3(64), 256, 0, stream>>>(Nacc, Bt4);

    // out = relu(h @ Bt4^T + bo), K=768 (B-chunk-resident, A-streamed)
    final_v2<<<dim3(64, 2), 256, 0, stream>>>(h, Bt4, bo, out);
}